// Round 1
// baseline (25343.729 us; speedup 1.0000x reference)
//
#include <hip/hip_runtime.h>

// VanillaRNN: S=512, I=1, H=256, C=10, B=2048, all fp32.
// h:[256, B] recurrence; batch independent -> 256 blocks x 8 batch, all 512
// steps inside one kernel. W_hh register-resident (512 thr x 4rows x 32cols).
// h in double-buffered, bank-swizzled LDS. j-split reduced via DPP butterfly.

#define SEQ  512
#define HID  256
#define NCLS 10
#define NB   8      // batch per block
#define NT   512    // threads per block (8 waves)

template <int CTRL>
__device__ __forceinline__ float dpp_xor_add(float v) {
    int mv = __builtin_amdgcn_update_dpp(0, __float_as_int(v), CTRL, 0xf, 0xf, false);
    return v + __int_as_float(mv);
}

__device__ __forceinline__ float fast_tanh(float z) {
    // tanh(z) = 1 - 2/(e^{2z}+1); exp overflow/underflow saturate correctly.
    float e = __expf(2.0f * z);
    return 1.0f - 2.0f / (e + 1.0f);
}

// h LDS layout: phys(j,b) = j*8 + (j>>5)*4 + b  (swizzle -> conflict-free
// broadcast reads: bank = (4*jg + 8k + b) & 31, distinct per jg)
__global__ __launch_bounds__(NT, 2) void rnn_fused(
    const float* __restrict__ x,     // [B, S]
    const float* __restrict__ W_hx,  // [H, 1]
    const float* __restrict__ W_hh,  // [H, H]
    const float* __restrict__ W_ph,  // [C, H]
    const float* __restrict__ b_h,   // [H]
    const float* __restrict__ b_p,   // [C]
    float* __restrict__ out)         // [B, C]
{
    __shared__ __align__(16) float h_lds[2][2080];
    __shared__ __align__(16) float x_lds[SEQ][NB];   // [t][b]

    const int tid  = threadIdx.x;
    const int lane = tid & 63;
    const int wave = tid >> 6;
    // jg from lane bits {0,1,3} (DPP-reducible); rg from bits {2,4,5} + wave
    const int jg = (lane & 3) | ((lane & 8) >> 1);                    // 0..7
    const int rg = wave * 8 + ((lane >> 4) << 1) + ((lane & 4) >> 2); // 0..63
    const int r0 = rg * 4;      // rows r0..r0+3
    const int j0 = jg * 32;     // cols j0..j0+31
    const int b0 = blockIdx.x * NB;

    // ---- stage W_hh slice into registers: w[4][32] ----
    float w[4][32];
#pragma unroll
    for (int r = 0; r < 4; ++r) {
        const float4* wp = (const float4*)&W_hh[(r0 + r) * HID + j0];
#pragma unroll
        for (int kk = 0; kk < 8; ++kk) {
            float4 v = wp[kk];
            w[r][kk * 4 + 0] = v.x; w[r][kk * 4 + 1] = v.y;
            w[r][kk * 4 + 2] = v.z; w[r][kk * 4 + 3] = v.w;
        }
    }
    float wx[4], bh[4];
#pragma unroll
    for (int r = 0; r < 4; ++r) { wx[r] = W_hx[r0 + r]; bh[r] = b_h[r0 + r]; }

    // ---- stage x transposed into LDS: x_lds[t][b] = x[b0+b][t] ----
    for (int i = tid; i < NB * SEQ / 4; i += NT) {
        int b  = i >> 7;            // / (SEQ/4)
        int t4 = (i & 127) * 4;
        float4 v = *(const float4*)&x[(b0 + b) * SEQ + t4];
        x_lds[t4 + 0][b] = v.x; x_lds[t4 + 1][b] = v.y;
        x_lds[t4 + 2][b] = v.z; x_lds[t4 + 3][b] = v.w;
    }
    // ---- h0 = 0 ----
    for (int i = tid; i < 2 * 2080; i += NT) ((float*)h_lds)[i] = 0.0f;
    __syncthreads();

    int cur = 0;
    for (int t = 0; t < SEQ; ++t) {
        float4 xv0 = *(const float4*)&x_lds[t][0];
        float4 xv1 = *(const float4*)&x_lds[t][4];

        float acc[4][NB];
#pragma unroll
        for (int r = 0; r < 4; ++r)
#pragma unroll
            for (int b = 0; b < NB; ++b) acc[r][b] = 0.0f;

        // thread's h window is contiguous: float offset 260*jg + 8k
        const float4* hp = (const float4*)&h_lds[cur][260 * jg];
#pragma unroll
        for (int k = 0; k < 32; ++k) {
            float4 h0 = hp[2 * k];
            float4 h1 = hp[2 * k + 1];
#pragma unroll
            for (int r = 0; r < 4; ++r) {
                float wv = w[r][k];
                acc[r][0] += wv * h0.x; acc[r][1] += wv * h0.y;
                acc[r][2] += wv * h0.z; acc[r][3] += wv * h0.w;
                acc[r][4] += wv * h1.x; acc[r][5] += wv * h1.y;
                acc[r][6] += wv * h1.z; acc[r][7] += wv * h1.w;
            }
        }

        // butterfly all-reduce over the 8 jg lanes (lane bits 0,1,3) on VALU
#pragma unroll
        for (int r = 0; r < 4; ++r)
#pragma unroll
            for (int b = 0; b < NB; ++b) {
                float v = acc[r][b];
                v = dpp_xor_add<0xB1>(v);    // quad_perm(1,0,3,2): xor 1
                v = dpp_xor_add<0x4E>(v);    // quad_perm(2,3,0,1): xor 2
                v = dpp_xor_add<0x128>(v);   // row_ror:8          : xor 8
                acc[r][b] = v;
            }

        // lane jg finalizes row r0+(jg>>1), batch quad (jg&1)*4
        float s0 = 0, s1 = 0, s2 = 0, s3 = 0, wxs = 0, bhs = 0;
#pragma unroll
        for (int g = 0; g < 8; ++g)
            if (jg == g) {
                const int rr = g >> 1, bb = (g & 1) * 4;
                s0 = acc[rr][bb + 0]; s1 = acc[rr][bb + 1];
                s2 = acc[rr][bb + 2]; s3 = acc[rr][bb + 3];
                wxs = wx[rr]; bhs = bh[rr];
            }
        float4 xv = (jg & 1) ? xv1 : xv0;

        const int nxt  = cur ^ 1;
        const int wrow = r0 + (jg >> 1);
        const int woff = wrow * 8 + (wrow >> 5) * 4 + (jg & 1) * 4;
        float4 hnew;
        hnew.x = fast_tanh(s0 + wxs * xv.x + bhs);
        hnew.y = fast_tanh(s1 + wxs * xv.y + bhs);
        hnew.z = fast_tanh(s2 + wxs * xv.z + bhs);
        hnew.w = fast_tanh(s3 + wxs * xv.w + bhs);
        *(float4*)&h_lds[nxt][woff] = hnew;
        cur = nxt;
        __syncthreads();
    }

    // ---- epilogue: out[b][c] = b_p[c] + sum_j W_ph[c][j] * h[j][b] ----
    if (tid < NB * NCLS) {
        int b = tid / NCLS;
        int c = tid % NCLS;
        float sum = b_p[c];
        for (int j = 0; j < HID; ++j)
            sum += W_ph[c * HID + j] * h_lds[cur][j * 8 + (j >> 5) * 4 + b];
        out[(b0 + b) * NCLS + c] = sum;
    }
}

extern "C" void kernel_launch(void* const* d_in, const int* in_sizes, int n_in,
                              void* d_out, int out_size, void* d_ws, size_t ws_size,
                              hipStream_t stream) {
    const float* x    = (const float*)d_in[0];
    const float* W_hx = (const float*)d_in[1];
    const float* W_hh = (const float*)d_in[2];
    const float* W_ph = (const float*)d_in[3];
    const float* b_h  = (const float*)d_in[4];
    const float* b_p  = (const float*)d_in[5];
    float* out = (float*)d_out;

    rnn_fused<<<dim3(2048 / NB), dim3(NT), 0, stream>>>(
        x, W_hx, W_hh, W_ph, b_h, b_p, out);
}